// Round 1
// baseline (446.246 us; speedup 1.0000x reference)
//
#include <hip/hip_runtime.h>
#include <hip/hip_bf16.h>
#include <cstdio>

// Problem constants: B=2, S=1024, D=256, H=8, K=32
#define PB 2
#define PS 1024
#define PD 256
#define PH 8
#define PK 32
#define HB (PH*PB)          // 16
#define BS (PB*PS)          // 2048
#define EPS 1e-9f

// ---------------- kernel 1: Q/K projections + elu+1 -------------------------
// one block per (b,s) row; thread t computes head h=t>>5, k=t&31 for Q and K.
__global__ void k_proj_qk(const float* __restrict__ x,
                          const float* __restrict__ Wks,
                          const float* __restrict__ Wqs,
                          float* __restrict__ Q, float* __restrict__ Kf) {
    int bs  = blockIdx.x;          // 0..2047
    int tid = threadIdx.x;         // 0..255
    __shared__ float xs[PD];
    xs[tid] = x[bs*PD + tid];
    __syncthreads();
    int h = tid >> 5, kk = tid & 31;
    const float* wq = Wqs + h*(PD*PK) + kk;
    const float* wk = Wks + h*(PD*PK) + kk;
    float aq = 0.f, ak = 0.f;
#pragma unroll 8
    for (int d = 0; d < PD; ++d) {
        float xv = xs[d];
        aq = fmaf(xv, wq[d*PK], aq);
        ak = fmaf(xv, wk[d*PK], ak);
    }
    // elu(z)+1 = z+1 (z>0) else exp(z)
    aq = aq > 0.f ? aq + 1.f : expf(aq);
    ak = ak > 0.f ? ak + 1.f : expf(ak);
    int b = bs >> 10, s = bs & 1023;
    int idx = ((h*PB + b)*PS + s)*PK + kk;
    Q[idx]  = aq;
    Kf[idx] = ak;
}

// ---------------- kernel 2: cumsum of K' over s ------------------------------
// one block per (h,b); 8 chunks x 32 k-lanes, two-pass chunked scan.
__global__ void k_cumsum(const float* __restrict__ Kf, float* __restrict__ cumK) {
    int hb  = blockIdx.x;          // 0..15
    int tid = threadIdx.x;         // 0..255
    int c = tid >> 5, kk = tid & 31;
    const float* src = Kf   + hb*(PS*PK) + c*128*PK + kk;
    float*       dst = cumK + hb*(PS*PK) + c*128*PK + kk;
    float sum = 0.f;
#pragma unroll 8
    for (int i = 0; i < 128; ++i) sum += src[i*PK];
    __shared__ float ssum[8][32];
    ssum[c][kk] = sum;
    __syncthreads();
    float acc = 0.f;
    for (int j = 0; j < c; ++j) acc += ssum[j][kk];
#pragma unroll 8
    for (int i = 0; i < 128; ++i) { acc += src[i*PK]; dst[i*PK] = acc; }
}

// ---------------- kernel 3: den[hb,s] = q . cumK + EPS -----------------------
__global__ void k_den(const float* __restrict__ Q, const float* __restrict__ cumK,
                      float* __restrict__ den) {
    int i = blockIdx.x*256 + threadIdx.x;      // 0..16383 = (h,b,s)
    const float4* q  = (const float4*)(Q    + (size_t)i*PK);
    const float4* ck = (const float4*)(cumK + (size_t)i*PK);
    float acc = 0.f;
#pragma unroll
    for (int j = 0; j < 8; ++j) {
        float4 a = q[j], b = ck[j];
        acc += a.x*b.x + a.y*b.y + a.z*b.z + a.w*b.w;
    }
    den[i] = acc + EPS;
}

// ---------------- kernel 4: V projection (GEMM X @ Wv_h) ---------------------
// 64x64 tile, 256 thr, 4x4 per thread, K-step 16, transposed-A LDS.
__global__ void k_proj_v(const float* __restrict__ x, const float* __restrict__ Wvs,
                         float* __restrict__ V) {
    int e0 = blockIdx.x * 64;
    int m0 = blockIdx.y * 64;      // bs rows
    int h  = blockIdx.z;
    int tid = threadIdx.x, tx = tid & 15, ty = tid >> 4;
    alignas(16) __shared__ float AsT[16][68];
    alignas(16) __shared__ float Bs[16][68];
    const float* Ag = x + (size_t)m0*PD;
    const float* Bg = Wvs + (size_t)h*PD*PD;
    float acc[4][4] = {};
    for (int k0 = 0; k0 < PD; k0 += 16) {
        {   int r = tid >> 2, c4 = tid & 3;
            float4 a = *(const float4*)(Ag + r*PD + k0 + c4*4);
            AsT[c4*4+0][r] = a.x; AsT[c4*4+1][r] = a.y;
            AsT[c4*4+2][r] = a.z; AsT[c4*4+3][r] = a.w; }
        {   int r = tid >> 4, c = (tid & 15)*4;
            *(float4*)&Bs[r][c] = *(const float4*)(Bg + (k0+r)*PD + e0 + c); }
        __syncthreads();
#pragma unroll
        for (int k = 0; k < 16; ++k) {
            float4 av = *(const float4*)&AsT[k][ty*4];
            float4 bv = *(const float4*)&Bs[k][tx*4];
            float a4[4] = {av.x, av.y, av.z, av.w};
            float b4[4] = {bv.x, bv.y, bv.z, bv.w};
#pragma unroll
            for (int i = 0; i < 4; ++i)
#pragma unroll
                for (int j = 0; j < 4; ++j)
                    acc[i][j] = fmaf(a4[i], b4[j], acc[i][j]);
        }
        __syncthreads();
    }
    float* Cg = V + (size_t)h*BS*PD + (size_t)m0*PD;
#pragma unroll
    for (int i = 0; i < 4; ++i) {
        float4 o = {acc[i][0], acc[i][1], acc[i][2], acc[i][3]};
        *(float4*)(Cg + (ty*4+i)*PD + e0 + tx*4) = o;
    }
}

// ---------------- kernel 5: att tiles (Q'K'^T, causal, /den) -----------------
__global__ void k_att(const float* __restrict__ Q, const float* __restrict__ Kf,
                      const float* __restrict__ den, float* __restrict__ att) {
    int t0 = blockIdx.x * 64;
    int s0 = blockIdx.y * 64;
    int hb = blockIdx.z;
    int tid = threadIdx.x, tx = tid & 15, ty = tid >> 4;
    float* attb = att + (size_t)hb*PS*PS;
    if (t0 > s0) {                       // strictly upper tile: zeros
        float4 z = {0.f,0.f,0.f,0.f};
#pragma unroll
        for (int i = 0; i < 4; ++i) {
            int s = s0 + ty*4 + i;
            *(float4*)(attb + (size_t)s*PS + t0 + tx*4) = z;
        }
        return;
    }
    alignas(16) __shared__ float QsT[32][68];
    alignas(16) __shared__ float KsT[32][68];
    const float* Qg = Q  + (size_t)hb*PS*PK + s0*PK;
    const float* Kg = Kf + (size_t)hb*PS*PK + t0*PK;
#pragma unroll
    for (int m = 0; m < 8; ++m) {
        int flat = tid + m*256;          // 0..2047
        int r = flat >> 5, kk = flat & 31;
        QsT[kk][r] = Qg[flat];
        KsT[kk][r] = Kg[flat];
    }
    __syncthreads();
    float acc[4][4] = {};
#pragma unroll
    for (int kk = 0; kk < 32; ++kk) {
        float4 av = *(const float4*)&QsT[kk][ty*4];
        float4 bv = *(const float4*)&KsT[kk][tx*4];
        float a4[4] = {av.x, av.y, av.z, av.w};
        float b4[4] = {bv.x, bv.y, bv.z, bv.w};
#pragma unroll
        for (int i = 0; i < 4; ++i)
#pragma unroll
            for (int j = 0; j < 4; ++j)
                acc[i][j] = fmaf(a4[i], b4[j], acc[i][j]);
    }
#pragma unroll
    for (int i = 0; i < 4; ++i) {
        int s = s0 + ty*4 + i;
        float rd = 1.0f / den[hb*PS + s];
        int t = t0 + tx*4;
        float4 o;
        o.x = (t+0 <= s) ? acc[i][0]*rd : 0.f;
        o.y = (t+1 <= s) ? acc[i][1]*rd : 0.f;
        o.z = (t+2 <= s) ? acc[i][2]*rd : 0.f;
        o.w = (t+3 <= s) ? acc[i][3]*rd : 0.f;
        *(float4*)(attb + (size_t)s*PS + t) = o;
    }
}

// ---------------- kernel 6: node = att @ V (triangular GEMM) -----------------
__global__ void k_node(const float* __restrict__ att, const float* __restrict__ V,
                       float* __restrict__ node) {
    int e0 = blockIdx.x * 64;
    int s0 = blockIdx.y * 64;
    int hb = blockIdx.z;
    int tid = threadIdx.x, tx = tid & 15, ty = tid >> 4;
    alignas(16) __shared__ float AsT[16][68];
    alignas(16) __shared__ float Bs[16][68];
    const float* Ag = att + (size_t)hb*PS*PS + (size_t)s0*PS;
    const float* Bg = V   + (size_t)hb*PS*PD;
    float acc[4][4] = {};
    int kmax = s0 + 64;                  // causal: att[s,t]=0 for t>s
    for (int k0 = 0; k0 < kmax; k0 += 16) {
        {   int r = tid >> 2, c4 = tid & 3;
            float4 a = *(const float4*)(Ag + (size_t)r*PS + k0 + c4*4);
            AsT[c4*4+0][r] = a.x; AsT[c4*4+1][r] = a.y;
            AsT[c4*4+2][r] = a.z; AsT[c4*4+3][r] = a.w; }
        {   int r = tid >> 4, c = (tid & 15)*4;
            *(float4*)&Bs[r][c] = *(const float4*)(Bg + (size_t)(k0+r)*PD + e0 + c); }
        __syncthreads();
#pragma unroll
        for (int k = 0; k < 16; ++k) {
            float4 av = *(const float4*)&AsT[k][ty*4];
            float4 bv = *(const float4*)&Bs[k][tx*4];
            float a4[4] = {av.x, av.y, av.z, av.w};
            float b4[4] = {bv.x, bv.y, bv.z, bv.w};
#pragma unroll
            for (int i = 0; i < 4; ++i)
#pragma unroll
                for (int j = 0; j < 4; ++j)
                    acc[i][j] = fmaf(a4[i], b4[j], acc[i][j]);
        }
        __syncthreads();
    }
    float* Cg = node + (size_t)hb*PS*PD + (size_t)s0*PD;
#pragma unroll
    for (int i = 0; i < 4; ++i) {
        float4 o = {acc[i][0], acc[i][1], acc[i][2], acc[i][3]};
        *(float4*)(Cg + (ty*4+i)*PD + e0 + tx*4) = o;
    }
}

// ---------------- kernel 7: out partials = node_flat @ Wo_flat (K-split) -----
__global__ void k_out_part(const float* __restrict__ node, const float* __restrict__ Wo,
                           float* __restrict__ part) {
    int e0 = blockIdx.x * 64;
    int m0 = blockIdx.y * 64;            // bs rows
    int ks = blockIdx.z;                 // 0..3, K chunk of 512
    int tid = threadIdx.x, tx = tid & 15, ty = tid >> 4;
    alignas(16) __shared__ float AsT[16][68];
    alignas(16) __shared__ float Bs[16][68];
    float acc[4][4] = {};
    int kbeg = ks*512, kend = kbeg + 512;
    for (int k0 = kbeg; k0 < kend; k0 += 16) {
        {   int r = tid >> 2, c4 = tid & 3;
            int kidx = k0 + c4*4;
            int h = kidx >> 8, d = kidx & 255;
            float4 a = *(const float4*)(node + (size_t)h*BS*PD + (size_t)(m0+r)*PD + d);
            AsT[c4*4+0][r] = a.x; AsT[c4*4+1][r] = a.y;
            AsT[c4*4+2][r] = a.z; AsT[c4*4+3][r] = a.w; }
        {   int r = tid >> 4, c = (tid & 15)*4;
            *(float4*)&Bs[r][c] = *(const float4*)(Wo + (size_t)(k0+r)*PD + e0 + c); }
        __syncthreads();
#pragma unroll
        for (int k = 0; k < 16; ++k) {
            float4 av = *(const float4*)&AsT[k][ty*4];
            float4 bv = *(const float4*)&Bs[k][tx*4];
            float a4[4] = {av.x, av.y, av.z, av.w};
            float b4[4] = {bv.x, bv.y, bv.z, bv.w};
#pragma unroll
            for (int i = 0; i < 4; ++i)
#pragma unroll
                for (int j = 0; j < 4; ++j)
                    acc[i][j] = fmaf(a4[i], b4[j], acc[i][j]);
        }
        __syncthreads();
    }
    float* Cg = part + (size_t)ks*BS*PD + (size_t)m0*PD;
#pragma unroll
    for (int i = 0; i < 4; ++i) {
        float4 o = {acc[i][0], acc[i][1], acc[i][2], acc[i][3]};
        *(float4*)(Cg + (ty*4+i)*PD + e0 + tx*4) = o;
    }
}

// ---------------- kernel 8: reduce 4 partials -> out --------------------------
__global__ void k_reduce(const float* __restrict__ part, float* __restrict__ out) {
    int i = blockIdx.x*256 + threadIdx.x;      // float4 index, 0..131071
    const float4* p = (const float4*)part;
    float4 a = p[i], b = p[131072 + i], c = p[262144 + i], d = p[393216 + i];
    float4 o = {a.x+b.x+c.x+d.x, a.y+b.y+c.y+d.y, a.z+b.z+c.z+d.z, a.w+b.w+c.w+d.w};
    ((float4*)out)[i] = o;
}

// ---------------- launch ------------------------------------------------------
extern "C" void kernel_launch(void* const* d_in, const int* in_sizes, int n_in,
                              void* d_out, int out_size, void* d_ws, size_t ws_size,
                              hipStream_t stream) {
    const float* x   = (const float*)d_in[0];
    const float* Wks = (const float*)d_in[1];
    const float* Wqs = (const float*)d_in[2];
    const float* Wvs = (const float*)d_in[3];
    const float* Wo  = (const float*)d_in[4];

    float* out = (float*)d_out;                     // [B,S,D] = 524288
    float* att = (float*)d_out + (size_t)PB*PS*PD;  // [H,B,S,S]

    // workspace layout (floats)
    // part (2,097,152) reuses [0..) region: Q/K/cumK/den (+V head) are dead
    // by the time k_out_part runs (stream-ordered).
    float* ws = (float*)d_ws;
    float* Q    = ws + 0;                //   524,288
    float* Kf   = ws + 524288;           //   524,288
    float* cumK = ws + 1048576;          //   524,288
    float* den  = ws + 1572864;          //    16,384
    float* V    = ws + 1589248;          // 4,194,304
    float* node = ws + 5783552;          // 4,194,304
    float* part = ws + 0;                // 2,097,152 (reuse)
    const size_t needed = (size_t)9977856 * 4;
    if (ws_size < needed) {
        fprintf(stderr, "kernel_launch: ws_size %zu < needed %zu\n", ws_size, needed);
        return;
    }

    k_proj_qk<<<BS, 256, 0, stream>>>(x, Wks, Wqs, Q, Kf);
    k_cumsum<<<HB, 256, 0, stream>>>(Kf, cumK);
    k_den<<<64, 256, 0, stream>>>(Q, cumK, den);
    k_proj_v<<<dim3(4, 32, PH), 256, 0, stream>>>(x, Wvs, V);
    k_att<<<dim3(16, 16, HB), 256, 0, stream>>>(Q, Kf, den, att);
    k_node<<<dim3(4, 16, HB), 256, 0, stream>>>(att, V, node);
    k_out_part<<<dim3(4, 32, 4), 256, 0, stream>>>(node, Wo, part);
    k_reduce<<<512, 256, 0, stream>>>(part, out);
}

// Round 2
// 325.829 us; speedup vs baseline: 1.3696x; 1.3696x over previous
//
#include <hip/hip_runtime.h>
#include <hip/hip_bf16.h>
#include <cstdio>

// Problem constants: B=2, S=1024, D=256, H=8, K=32
#define PB 2
#define PS 1024
#define PD 256
#define PH 8
#define PK 32
#define HB (PH*PB)          // 16
#define BS (PB*PS)          // 2048
#define EPS 1e-9f

// ---------------- kernel 1: Q/K projections + elu+1 -------------------------
__global__ void k_proj_qk(const float* __restrict__ x,
                          const float* __restrict__ Wks,
                          const float* __restrict__ Wqs,
                          float* __restrict__ Q, float* __restrict__ Kf) {
    int bs  = blockIdx.x;          // 0..2047
    int tid = threadIdx.x;         // 0..255
    __shared__ float xs[PD];
    xs[tid] = x[bs*PD + tid];
    __syncthreads();
    int h = tid >> 5, kk = tid & 31;
    const float* wq = Wqs + h*(PD*PK) + kk;
    const float* wk = Wks + h*(PD*PK) + kk;
    float aq = 0.f, ak = 0.f;
#pragma unroll 8
    for (int d = 0; d < PD; ++d) {
        float xv = xs[d];
        aq = fmaf(xv, wq[d*PK], aq);
        ak = fmaf(xv, wk[d*PK], ak);
    }
    aq = aq > 0.f ? aq + 1.f : expf(aq);
    ak = ak > 0.f ? ak + 1.f : expf(ak);
    int b = bs >> 10, s = bs & 1023;
    int idx = ((h*PB + b)*PS + s)*PK + kk;
    Q[idx]  = aq;
    Kf[idx] = ak;
}

// ---------------- kernel 2: cumsum of K' over s ------------------------------
__global__ void k_cumsum(const float* __restrict__ Kf, float* __restrict__ cumK) {
    int hb  = blockIdx.x;          // 0..15
    int tid = threadIdx.x;         // 0..255
    int c = tid >> 5, kk = tid & 31;
    const float* src = Kf   + hb*(PS*PK) + c*128*PK + kk;
    float*       dst = cumK + hb*(PS*PK) + c*128*PK + kk;
    float sum = 0.f;
#pragma unroll 8
    for (int i = 0; i < 128; ++i) sum += src[i*PK];
    __shared__ float ssum[8][32];
    ssum[c][kk] = sum;
    __syncthreads();
    float acc = 0.f;
    for (int j = 0; j < c; ++j) acc += ssum[j][kk];
#pragma unroll 8
    for (int i = 0; i < 128; ++i) { acc += src[i*PK]; dst[i*PK] = acc; }
}

// ---------------- kernel 3: den[hb,s] = q . cumK + EPS -----------------------
__global__ void k_den(const float* __restrict__ Q, const float* __restrict__ cumK,
                      float* __restrict__ den) {
    int i = blockIdx.x*256 + threadIdx.x;      // 0..16383 = (h,b,s)
    const float4* q  = (const float4*)(Q    + (size_t)i*PK);
    const float4* ck = (const float4*)(cumK + (size_t)i*PK);
    float acc = 0.f;
#pragma unroll
    for (int j = 0; j < 8; ++j) {
        float4 a = q[j], b = ck[j];
        acc += a.x*b.x + a.y*b.y + a.z*b.z + a.w*b.w;
    }
    den[i] = acc + EPS;
}

// ---------------- kernel 4: V projection (GEMM X @ Wv_h) ---------------------
__global__ void k_proj_v(const float* __restrict__ x, const float* __restrict__ Wvs,
                         float* __restrict__ V) {
    int e0 = blockIdx.x * 64;
    int m0 = blockIdx.y * 64;      // bs rows
    int h  = blockIdx.z;
    int tid = threadIdx.x, tx = tid & 15, ty = tid >> 4;
    alignas(16) __shared__ float AsT[16][68];
    alignas(16) __shared__ float Bs[16][68];
    const float* Ag = x + (size_t)m0*PD;
    const float* Bg = Wvs + (size_t)h*PD*PD;
    float acc[4][4] = {};
    for (int k0 = 0; k0 < PD; k0 += 16) {
        {   int r = tid >> 2, c4 = tid & 3;
            float4 a = *(const float4*)(Ag + r*PD + k0 + c4*4);
            AsT[c4*4+0][r] = a.x; AsT[c4*4+1][r] = a.y;
            AsT[c4*4+2][r] = a.z; AsT[c4*4+3][r] = a.w; }
        {   int r = tid >> 4, c = (tid & 15)*4;
            *(float4*)&Bs[r][c] = *(const float4*)(Bg + (k0+r)*PD + e0 + c); }
        __syncthreads();
#pragma unroll
        for (int k = 0; k < 16; ++k) {
            float4 av = *(const float4*)&AsT[k][ty*4];
            float4 bv = *(const float4*)&Bs[k][tx*4];
            float a4[4] = {av.x, av.y, av.z, av.w};
            float b4[4] = {bv.x, bv.y, bv.z, bv.w};
#pragma unroll
            for (int i = 0; i < 4; ++i)
#pragma unroll
                for (int j = 0; j < 4; ++j)
                    acc[i][j] = fmaf(a4[i], b4[j], acc[i][j]);
        }
        __syncthreads();
    }
    float* Cg = V + (size_t)h*BS*PD + (size_t)m0*PD;
#pragma unroll
    for (int i = 0; i < 4; ++i) {
        float4 o = {acc[i][0], acc[i][1], acc[i][2], acc[i][3]};
        *(float4*)(Cg + (ty*4+i)*PD + e0 + tx*4) = o;
    }
}

// ---------------- kernel 5: zero-fill strictly-upper att tiles ---------------
// Full-line float4 stores; also serves as a write-pattern control experiment.
__global__ void k_att_zero(float* __restrict__ att) {
    int st = blockIdx.x;           // 0..14 (row tile)
    int hb = blockIdx.y;
    int s0 = st * 64;
    int c0 = s0 + 64;              // first zero column
    int nz4 = (PS - c0) >> 2;      // float4 per row
    float* base = att + (size_t)hb*PS*PS + (size_t)s0*PS + c0;
    int r = threadIdx.x >> 2;      // 64 rows, 4 threads per row
    int l4 = threadIdx.x & 3;
    float4 z = {0.f, 0.f, 0.f, 0.f};
    for (int c4 = l4; c4 < nz4; c4 += 4)
        *(float4*)(base + (size_t)r*PS + c4*4) = z;
}

// ---------------- kernel 6: fused att-write + node accumulation -------------
// grid (eh=2, s-tile=16 permuted, hb=16); 256 threads; 50.5 KB LDS.
// Per block: stage Q tile; loop t-tiles <= s-tile:
//   P = Q'K'^T (fp32 regs) -> mask diag, scale 1/den -> write att tile (eh==0)
//   -> store P^T to LDS -> node_acc += P @ V (V staged in 32-row chunks).
__global__ __launch_bounds__(256) void k_fused(const float* __restrict__ Q,
                                               const float* __restrict__ Kf,
                                               const float* __restrict__ den,
                                               const float* __restrict__ V,
                                               float* __restrict__ att,
                                               float* __restrict__ node) {
    int eh = blockIdx.x;                       // 0,1 -> e cols [eh*128, +128)
    int yy = blockIdx.y;
    int st = (yy & 1) ? (15 - (yy >> 1)) : (yy >> 1);   // interleave heavy/light
    int hb = blockIdx.z;
    int s0 = st * 64;
    int e0 = eh * 128;
    int tid = threadIdx.x, tx = tid & 15, ty = tid >> 4;

    alignas(16) __shared__ float QsT[32][68];   // [k][s-row]
    alignas(16) __shared__ float KsT[32][68];   // [k][t-row]
    alignas(16) __shared__ float PT[64][68];    // [t][s-row]
    alignas(16) __shared__ float Vs[32][132];   // [t-chunk-row][e (128)]
    __shared__ float rden[64];

    const float* Qg    = Q  + (size_t)hb*PS*PK + (size_t)s0*PK;
    const float* Kbase = Kf + (size_t)hb*PS*PK;
    const float* Vbase = V  + (size_t)hb*PS*PD + e0;
    float* attb = att + (size_t)hb*PS*PS;

#pragma unroll
    for (int m = 0; m < 8; ++m) {
        int flat = tid + m*256;                 // 0..2047
        QsT[flat & 31][flat >> 5] = Qg[flat];
    }
    if (tid < 64) rden[tid] = 1.0f / den[hb*PS + s0 + tid];

    float acc2[4][8] = {};                      // node tile: 4 s-rows x 8 e-cols

    for (int t0 = 0; t0 <= s0; t0 += 64) {
        __syncthreads();                        // prev GEMM2 done w/ PT,Vs; GEMM1 done w/ KsT
        const float* Kg = Kbase + (size_t)t0*PK;
#pragma unroll
        for (int m = 0; m < 8; ++m) {
            int flat = tid + m*256;
            KsT[flat & 31][flat >> 5] = Kg[flat];
        }
        __syncthreads();                        // KsT ready (QsT/rden ready 1st iter)

        float acc1[4][4] = {};
#pragma unroll
        for (int kk = 0; kk < 32; ++kk) {
            float4 av = *(const float4*)&QsT[kk][ty*4];
            float4 bv = *(const float4*)&KsT[kk][tx*4];
            float a4[4] = {av.x, av.y, av.z, av.w};
            float b4[4] = {bv.x, bv.y, bv.z, bv.w};
#pragma unroll
            for (int i = 0; i < 4; ++i)
#pragma unroll
                for (int j = 0; j < 4; ++j)
                    acc1[i][j] = fmaf(a4[i], b4[j], acc1[i][j]);
        }

        bool diag = (t0 == s0);
#pragma unroll
        for (int i = 0; i < 4; ++i) {
            int srow = ty*4 + i;
            float rd = rden[srow];
            float v0 = acc1[i][0]*rd, v1 = acc1[i][1]*rd,
                  v2 = acc1[i][2]*rd, v3 = acc1[i][3]*rd;
            if (diag) {
                int s = s0 + srow, t = t0 + tx*4;
                v0 = (t+0 <= s) ? v0 : 0.f;
                v1 = (t+1 <= s) ? v1 : 0.f;
                v2 = (t+2 <= s) ? v2 : 0.f;
                v3 = (t+3 <= s) ? v3 : 0.f;
            }
            PT[tx*4+0][srow] = v0;
            PT[tx*4+1][srow] = v1;
            PT[tx*4+2][srow] = v2;
            PT[tx*4+3][srow] = v3;
            if (eh == 0) {
                float4 o = {v0, v1, v2, v3};
                *(float4*)(attb + (size_t)(s0+srow)*PS + t0 + tx*4) = o;
            }
        }

#pragma unroll
        for (int ch = 0; ch < 2; ++ch) {
            __syncthreads();                    // ch0: PT complete; Vs free
            const float* Vg = Vbase + (size_t)(t0 + ch*32)*PD;
#pragma unroll
            for (int m = 0; m < 4; ++m) {
                int f4 = tid + m*256;           // 0..1023
                int r = f4 >> 5, c = (f4 & 31)*4;
                *(float4*)&Vs[r][c] = *(const float4*)(Vg + (size_t)r*PD + c);
            }
            __syncthreads();                    // Vs ready
#pragma unroll
            for (int k = 0; k < 32; ++k) {
                float4 a  = *(const float4*)&PT[ch*32 + k][ty*4];
                float4 b0 = *(const float4*)&Vs[k][tx*4];
                float4 b1 = *(const float4*)&Vs[k][64 + tx*4];
                float a4[4] = {a.x, a.y, a.z, a.w};
                float bl[8] = {b0.x, b0.y, b0.z, b0.w, b1.x, b1.y, b1.z, b1.w};
#pragma unroll
                for (int i = 0; i < 4; ++i)
#pragma unroll
                    for (int j = 0; j < 8; ++j)
                        acc2[i][j] = fmaf(a4[i], bl[j], acc2[i][j]);
            }
        }
    }

    float* nodep = node + (size_t)hb*PS*PD + (size_t)s0*PD + e0;
#pragma unroll
    for (int i = 0; i < 4; ++i) {
        float4 o0 = {acc2[i][0], acc2[i][1], acc2[i][2], acc2[i][3]};
        float4 o1 = {acc2[i][4], acc2[i][5], acc2[i][6], acc2[i][7]};
        *(float4*)(nodep + (size_t)(ty*4+i)*PD + tx*4)      = o0;
        *(float4*)(nodep + (size_t)(ty*4+i)*PD + 64 + tx*4) = o1;
    }
}

// ---------------- kernel 7: out partials = node_flat @ Wo_flat (K-split) -----
__global__ void k_out_part(const float* __restrict__ node, const float* __restrict__ Wo,
                           float* __restrict__ part) {
    int e0 = blockIdx.x * 64;
    int m0 = blockIdx.y * 64;            // bs rows
    int ks = blockIdx.z;                 // 0..3, K chunk of 512
    int tid = threadIdx.x, tx = tid & 15, ty = tid >> 4;
    alignas(16) __shared__ float AsT[16][68];
    alignas(16) __shared__ float Bs[16][68];
    float acc[4][4] = {};
    int kbeg = ks*512, kend = kbeg + 512;
    for (int k0 = kbeg; k0 < kend; k0 += 16) {
        {   int r = tid >> 2, c4 = tid & 3;
            int kidx = k0 + c4*4;
            int h = kidx >> 8, d = kidx & 255;
            float4 a = *(const float4*)(node + (size_t)h*BS*PD + (size_t)(m0+r)*PD + d);
            AsT[c4*4+0][r] = a.x; AsT[c4*4+1][r] = a.y;
            AsT[c4*4+2][r] = a.z; AsT[c4*4+3][r] = a.w; }
        {   int r = tid >> 4, c = (tid & 15)*4;
            *(float4*)&Bs[r][c] = *(const float4*)(Wo + (size_t)(k0+r)*PD + e0 + c); }
        __syncthreads();
#pragma unroll
        for (int k = 0; k < 16; ++k) {
            float4 av = *(const float4*)&AsT[k][ty*4];
            float4 bv = *(const float4*)&Bs[k][tx*4];
            float a4[4] = {av.x, av.y, av.z, av.w};
            float b4[4] = {bv.x, bv.y, bv.z, bv.w};
#pragma unroll
            for (int i = 0; i < 4; ++i)
#pragma unroll
                for (int j = 0; j < 4; ++j)
                    acc[i][j] = fmaf(a4[i], b4[j], acc[i][j]);
        }
        __syncthreads();
    }
    float* Cg = part + (size_t)ks*BS*PD + (size_t)m0*PD;
#pragma unroll
    for (int i = 0; i < 4; ++i) {
        float4 o = {acc[i][0], acc[i][1], acc[i][2], acc[i][3]};
        *(float4*)(Cg + (ty*4+i)*PD + e0 + tx*4) = o;
    }
}

// ---------------- kernel 8: reduce 4 partials -> out --------------------------
__global__ void k_reduce(const float* __restrict__ part, float* __restrict__ out) {
    int i = blockIdx.x*256 + threadIdx.x;      // float4 index, 0..131071
    const float4* p = (const float4*)part;
    float4 a = p[i], b = p[131072 + i], c = p[262144 + i], d = p[393216 + i];
    float4 o = {a.x+b.x+c.x+d.x, a.y+b.y+c.y+d.y, a.z+b.z+c.z+d.z, a.w+b.w+c.w+d.w};
    ((float4*)out)[i] = o;
}

// ---------------- launch ------------------------------------------------------
extern "C" void kernel_launch(void* const* d_in, const int* in_sizes, int n_in,
                              void* d_out, int out_size, void* d_ws, size_t ws_size,
                              hipStream_t stream) {
    const float* x   = (const float*)d_in[0];
    const float* Wks = (const float*)d_in[1];
    const float* Wqs = (const float*)d_in[2];
    const float* Wvs = (const float*)d_in[3];
    const float* Wo  = (const float*)d_in[4];

    float* out = (float*)d_out;                     // [B,S,D] = 524288
    float* att = (float*)d_out + (size_t)PB*PS*PD;  // [H,B,S,S]

    float* ws = (float*)d_ws;
    float* Q    = ws + 0;                //   524,288
    float* Kf   = ws + 524288;           //   524,288
    float* cumK = ws + 1048576;          //   524,288
    float* den  = ws + 1572864;          //    16,384
    float* V    = ws + 1589248;          // 4,194,304
    float* node = ws + 5783552;          // 4,194,304
    float* part = ws + 0;                // 2,097,152 (reuse: Q/Kf/cumK/den dead)
    const size_t needed = (size_t)9977856 * 4;
    if (ws_size < needed) {
        fprintf(stderr, "kernel_launch: ws_size %zu < needed %zu\n", ws_size, needed);
        return;
    }

    k_proj_qk<<<BS, 256, 0, stream>>>(x, Wks, Wqs, Q, Kf);
    k_cumsum<<<HB, 256, 0, stream>>>(Kf, cumK);
    k_den<<<64, 256, 0, stream>>>(Q, cumK, den);
    k_proj_v<<<dim3(4, 32, PH), 256, 0, stream>>>(x, Wvs, V);
    k_att_zero<<<dim3(15, HB), 256, 0, stream>>>(att);
    k_fused<<<dim3(2, 16, HB), 256, 0, stream>>>(Q, Kf, den, V, att, node);
    k_out_part<<<dim3(4, 32, 4), 256, 0, stream>>>(node, Wo, part);
    k_reduce<<<512, 256, 0, stream>>>(part, out);
}

// Round 3
// 162.738 us; speedup vs baseline: 2.7421x; 2.0022x over previous
//
#include <hip/hip_runtime.h>
#include <hip/hip_bf16.h>
#include <cstdio>

// Problem constants: B=2, S=1024, D=256, H=8, K=32
#define PB 2
#define PS 1024
#define PD 256
#define PH 8
#define PK 32
#define HB (PH*PB)          // 16
#define BS (PB*PS)          // 2048
#define EPS 1e-9f

typedef __attribute__((ext_vector_type(8))) short bf16x8;
typedef __attribute__((ext_vector_type(4))) float f32x4;

__device__ inline unsigned short f2bf(float f) {
    __hip_bfloat16 h = __float2bfloat16(f);
    return *reinterpret_cast<unsigned short*>(&h);
}

// ---------------- kernel 1: Q/K projections + elu+1 (f32 + bf16 copies) -----
__global__ void k_proj_qk(const float* __restrict__ x,
                          const float* __restrict__ Wks,
                          const float* __restrict__ Wqs,
                          float* __restrict__ Q, float* __restrict__ Kf,
                          unsigned short* __restrict__ Qb,
                          unsigned short* __restrict__ Kb) {
    int bs  = blockIdx.x;          // 0..2047
    int tid = threadIdx.x;         // 0..255
    __shared__ float xs[PD];
    xs[tid] = x[bs*PD + tid];
    __syncthreads();
    int h = tid >> 5, kk = tid & 31;
    const float* wq = Wqs + h*(PD*PK) + kk;
    const float* wk = Wks + h*(PD*PK) + kk;
    float aq = 0.f, ak = 0.f;
#pragma unroll 8
    for (int d = 0; d < PD; ++d) {
        float xv = xs[d];
        aq = fmaf(xv, wq[d*PK], aq);
        ak = fmaf(xv, wk[d*PK], ak);
    }
    aq = aq > 0.f ? aq + 1.f : expf(aq);
    ak = ak > 0.f ? ak + 1.f : expf(ak);
    int b = bs >> 10, s = bs & 1023;
    int idx = ((h*PB + b)*PS + s)*PK + kk;
    Q[idx]  = aq;
    Kf[idx] = ak;
    Qb[idx] = f2bf(aq);
    Kb[idx] = f2bf(ak);
}

// ---------------- kernel 2: cumsum of K' over s ------------------------------
__global__ void k_cumsum(const float* __restrict__ Kf, float* __restrict__ cumK) {
    int hb  = blockIdx.x;          // 0..15
    int tid = threadIdx.x;         // 0..255
    int c = tid >> 5, kk = tid & 31;
    const float* src = Kf   + hb*(PS*PK) + c*128*PK + kk;
    float*       dst = cumK + hb*(PS*PK) + c*128*PK + kk;
    float sum = 0.f;
#pragma unroll 8
    for (int i = 0; i < 128; ++i) sum += src[i*PK];
    __shared__ float ssum[8][32];
    ssum[c][kk] = sum;
    __syncthreads();
    float acc = 0.f;
    for (int j = 0; j < c; ++j) acc += ssum[j][kk];
#pragma unroll 8
    for (int i = 0; i < 128; ++i) { acc += src[i*PK]; dst[i*PK] = acc; }
}

// ---------------- kernel 3: den[hb,s] = q . cumK + EPS -----------------------
__global__ void k_den(const float* __restrict__ Q, const float* __restrict__ cumK,
                      float* __restrict__ den) {
    int i = blockIdx.x*256 + threadIdx.x;      // 0..16383 = (h,b,s)
    const float4* q  = (const float4*)(Q    + (size_t)i*PK);
    const float4* ck = (const float4*)(cumK + (size_t)i*PK);
    float acc = 0.f;
#pragma unroll
    for (int j = 0; j < 8; ++j) {
        float4 a = q[j], b = ck[j];
        acc += a.x*b.x + a.y*b.y + a.z*b.z + a.w*b.w;
    }
    den[i] = acc + EPS;
}

// ---------------- kernel 4: V projection -> Vt bf16 tiled --------------------
// Vt layout: [h*32 + bsTile][e 256][t 64] bf16 (32KB tiles, contiguous).
__global__ void k_proj_v(const float* __restrict__ x, const float* __restrict__ Wvs,
                         unsigned short* __restrict__ Vt) {
    int e0 = blockIdx.x * 64;
    int m0 = blockIdx.y * 64;      // bs rows
    int h  = blockIdx.z;
    int tid = threadIdx.x, tx = tid & 15, ty = tid >> 4;
    alignas(16) __shared__ float AsT[16][68];
    alignas(16) __shared__ float Bs[16][68];
    const float* Ag = x + (size_t)m0*PD;
    const float* Bg = Wvs + (size_t)h*PD*PD;
    float acc[4][4] = {};
    for (int k0 = 0; k0 < PD; k0 += 16) {
        {   int r = tid >> 2, c4 = tid & 3;
            float4 a = *(const float4*)(Ag + r*PD + k0 + c4*4);
            AsT[c4*4+0][r] = a.x; AsT[c4*4+1][r] = a.y;
            AsT[c4*4+2][r] = a.z; AsT[c4*4+3][r] = a.w; }
        {   int r = tid >> 4, c = (tid & 15)*4;
            *(float4*)&Bs[r][c] = *(const float4*)(Bg + (k0+r)*PD + e0 + c); }
        __syncthreads();
#pragma unroll
        for (int k = 0; k < 16; ++k) {
            float4 av = *(const float4*)&AsT[k][ty*4];
            float4 bv = *(const float4*)&Bs[k][tx*4];
            float a4[4] = {av.x, av.y, av.z, av.w};
            float b4[4] = {bv.x, bv.y, bv.z, bv.w};
#pragma unroll
            for (int i = 0; i < 4; ++i)
#pragma unroll
                for (int j = 0; j < 4; ++j)
                    acc[i][j] = fmaf(a4[i], b4[j], acc[i][j]);
        }
        __syncthreads();
    }
    // store transposed bf16: Vt[tile][e][t], tile = h*32 + m0/64
    unsigned short* Cg = Vt + ((size_t)h*32 + blockIdx.y)*(256*64);
#pragma unroll
    for (int j = 0; j < 4; ++j) {
        ushort4 o;
        o.x = f2bf(acc[0][j]); o.y = f2bf(acc[1][j]);
        o.z = f2bf(acc[2][j]); o.w = f2bf(acc[3][j]);
        *(ushort4*)(Cg + (size_t)(e0 + tx*4 + j)*64 + ty*4) = o;
    }
}

// ---------------- kernel 5: zero-fill strictly-upper att tiles ---------------
__global__ void k_att_zero(float* __restrict__ att) {
    int st = blockIdx.x;           // 0..14 (row tile)
    int hb = blockIdx.y;
    int s0 = st * 64;
    int c0 = s0 + 64;              // first zero column
    int nz4 = (PS - c0) >> 2;      // float4 per row
    float* base = att + (size_t)hb*PS*PS + (size_t)s0*PS + c0;
    int r = threadIdx.x >> 2;      // 64 rows, 4 threads per row
    int l4 = threadIdx.x & 3;
    float4 z = {0.f, 0.f, 0.f, 0.f};
    for (int c4 = l4; c4 < nz4; c4 += 4)
        *(float4*)(base + (size_t)r*PS + c4*4) = z;
}

// ---------------- kernel 6: fused MFMA att + node ----------------------------
// grid (16 s-tiles permuted, 16 hb); 256 thr = 4 waves.
// GEMM1: P = Q'K'^T via mfma_16x16x32_bf16 (wave w = m-strip w).
//   scale 1/den, causal mask, write att f32, write P bf16 -> LDS.
// GEMM2: node += P @ V via mfma, wave w handles e-tiles 4w..4w+3,
//   Vt tile staged in LDS (stride 72 shorts: 16B-aligned, uniform banks).
__global__ __launch_bounds__(256) void k_fused(
    const unsigned short* __restrict__ Qb, const unsigned short* __restrict__ Kb,
    const float* __restrict__ den, const unsigned short* __restrict__ Vt,
    float* __restrict__ att, float* __restrict__ node)
{
    int yy = blockIdx.x;
    int st = (yy & 1) ? (15 - (yy >> 1)) : (yy >> 1);   // interleave heavy/light
    int hb = blockIdx.y;
    int s0 = st * 64;
    int tid = threadIdx.x;
    int w = tid >> 6, l15 = tid & 15, g = (tid >> 4) & 3;

    __shared__ unsigned short VtL[256*72];   // 36 KB
    __shared__ unsigned short PL[64*72];     // 9 KB
    __shared__ float rden[64];

    bf16x8 qf = *(const bf16x8*)(Qb + ((size_t)hb*PS + s0 + 16*w + l15)*PK + 8*g);
    if (tid < 64) rden[tid] = 1.0f / den[hb*PS + s0 + tid];

    f32x4 zf = {0.f, 0.f, 0.f, 0.f};
    f32x4 acc2[4][4];
#pragma unroll
    for (int i = 0; i < 4; ++i)
#pragma unroll
        for (int j = 0; j < 4; ++j) acc2[i][j] = zf;

    float* attb = att + (size_t)hb*PS*PS;

    for (int t0 = 0; t0 <= s0; t0 += 64) {
        __syncthreads();                       // prev GEMM2 done with VtL/PL
        // ---- stage Vt tile [256 e][64 t] bf16 (32 KB) ----
        const float4* src = (const float4*)(Vt + ((size_t)hb*16 + (t0 >> 6))*(256*64));
#pragma unroll
        for (int rep = 0; rep < 8; ++rep) {
            int idx = tid + rep*256;           // 0..2047
            float4 v = src[idx];
            int e = idx >> 3, q = idx & 7;
            *(float4*)(VtL + e*72 + q*8) = v;
        }
        // ---- GEMM1: P strip (rows 16w..16w+15) ----
        f32x4 p[4];
#pragma unroll
        for (int nt = 0; nt < 4; ++nt) {
            bf16x8 kf = *(const bf16x8*)(Kb + ((size_t)hb*PS + t0 + 16*nt + l15)*PK + 8*g);
            p[nt] = __builtin_amdgcn_mfma_f32_16x16x32_bf16(qf, kf, zf, 0, 0, 0);
        }
        bool diag = (t0 == s0);
        int rb = 16*w + 4*g;
#pragma unroll
        for (int nt = 0; nt < 4; ++nt) {
#pragma unroll
            for (int j = 0; j < 4; ++j) {
                int r = rb + j;                       // s within tile
                int t = t0 + 16*nt + l15;
                float v = p[nt][j] * rden[r];
                if (diag && t > s0 + r) v = 0.f;
                attb[(size_t)(s0 + r)*PS + t] = v;
                PL[r*72 + 16*nt + l15] = f2bf(v);
            }
        }
        __syncthreads();                       // VtL + PL ready
        // ---- GEMM2: wave w -> e-tiles 4w..4w+3, all 4 m-tiles ----
#pragma unroll
        for (int c = 0; c < 2; ++c) {
            bf16x8 af[4];
#pragma unroll
            for (int mt = 0; mt < 4; ++mt)
                af[mt] = *(const bf16x8*)(PL + (16*mt + l15)*72 + 32*c + 8*g);
#pragma unroll
            for (int ntl = 0; ntl < 4; ++ntl) {
                bf16x8 vf = *(const bf16x8*)(VtL + (16*(4*w + ntl) + l15)*72 + 32*c + 8*g);
#pragma unroll
                for (int mt = 0; mt < 4; ++mt)
                    acc2[mt][ntl] = __builtin_amdgcn_mfma_f32_16x16x32_bf16(af[mt], vf, acc2[mt][ntl], 0, 0, 0);
            }
        }
    }
    // ---- store node f32 ----
    float* np = node + (size_t)hb*PS*PD;
#pragma unroll
    for (int mt = 0; mt < 4; ++mt)
#pragma unroll
        for (int ntl = 0; ntl < 4; ++ntl)
#pragma unroll
            for (int j = 0; j < 4; ++j)
                np[(size_t)(s0 + 16*mt + 4*g + j)*PD + 64*w + 16*ntl + l15] = acc2[mt][ntl][j];
}

// ---------------- kernel 7: out partials = node_flat @ Wo_flat (K-split) -----
__global__ void k_out_part(const float* __restrict__ node, const float* __restrict__ Wo,
                           float* __restrict__ part) {
    int e0 = blockIdx.x * 64;
    int m0 = blockIdx.y * 64;            // bs rows
    int ks = blockIdx.z;                 // 0..3, K chunk of 512
    int tid = threadIdx.x, tx = tid & 15, ty = tid >> 4;
    alignas(16) __shared__ float AsT[16][68];
    alignas(16) __shared__ float Bs[16][68];
    float acc[4][4] = {};
    int kbeg = ks*512, kend = kbeg + 512;
    for (int k0 = kbeg; k0 < kend; k0 += 16) {
        {   int r = tid >> 2, c4 = tid & 3;
            int kidx = k0 + c4*4;
            int h = kidx >> 8, d = kidx & 255;
            float4 a = *(const float4*)(node + (size_t)h*BS*PD + (size_t)(m0+r)*PD + d);
            AsT[c4*4+0][r] = a.x; AsT[c4*4+1][r] = a.y;
            AsT[c4*4+2][r] = a.z; AsT[c4*4+3][r] = a.w; }
        {   int r = tid >> 4, c = (tid & 15)*4;
            *(float4*)&Bs[r][c] = *(const float4*)(Wo + (size_t)(k0+r)*PD + e0 + c); }
        __syncthreads();
#pragma unroll
        for (int k = 0; k < 16; ++k) {
            float4 av = *(const float4*)&AsT[k][ty*4];
            float4 bv = *(const float4*)&Bs[k][tx*4];
            float a4[4] = {av.x, av.y, av.z, av.w};
            float b4[4] = {bv.x, bv.y, bv.z, bv.w};
#pragma unroll
            for (int i = 0; i < 4; ++i)
#pragma unroll
                for (int j = 0; j < 4; ++j)
                    acc[i][j] = fmaf(a4[i], b4[j], acc[i][j]);
        }
        __syncthreads();
    }
    float* Cg = part + (size_t)ks*BS*PD + (size_t)m0*PD;
#pragma unroll
    for (int i = 0; i < 4; ++i) {
        float4 o = {acc[i][0], acc[i][1], acc[i][2], acc[i][3]};
        *(float4*)(Cg + (ty*4+i)*PD + e0 + tx*4) = o;
    }
}

// ---------------- kernel 8: reduce 4 partials -> out --------------------------
__global__ void k_reduce(const float* __restrict__ part, float* __restrict__ out) {
    int i = blockIdx.x*256 + threadIdx.x;      // float4 index, 0..131071
    const float4* p = (const float4*)part;
    float4 a = p[i], b = p[131072 + i], c = p[262144 + i], d = p[393216 + i];
    float4 o = {a.x+b.x+c.x+d.x, a.y+b.y+c.y+d.y, a.z+b.z+c.z+d.z, a.w+b.w+c.w+d.w};
    ((float4*)out)[i] = o;
}

// ---------------- launch ------------------------------------------------------
extern "C" void kernel_launch(void* const* d_in, const int* in_sizes, int n_in,
                              void* d_out, int out_size, void* d_ws, size_t ws_size,
                              hipStream_t stream) {
    const float* x   = (const float*)d_in[0];
    const float* Wks = (const float*)d_in[1];
    const float* Wqs = (const float*)d_in[2];
    const float* Wvs = (const float*)d_in[3];
    const float* Wo  = (const float*)d_in[4];

    float* out = (float*)d_out;                     // [B,S,D] = 524288
    float* att = (float*)d_out + (size_t)PB*PS*PD;  // [H,B,S,S]

    // workspace layout (float offsets)
    float* ws = (float*)d_ws;
    float*          Q    = ws + 0;         //   524,288
    float*          Kf   = ws + 524288;    //   524,288
    float*          cumK = ws + 1048576;   //   524,288
    float*          den  = ws + 1572864;   //    16,384
    unsigned short* Qb   = (unsigned short*)(ws + 1589248);  // 524,288 u16 (262,144 f)
    unsigned short* Kb   = (unsigned short*)(ws + 1851392);  // 524,288 u16 (262,144 f)
    unsigned short* Vt   = (unsigned short*)(ws + 2113536);  // 4,194,304 u16 (2,097,152 f)
    float*          node = ws + 4210688;   // 4,194,304
    float*          part = ws + 0;         // 2,097,152 (reuse: Q..Kb dead by then)
    const size_t needed = (size_t)8404992 * 4;
    if (ws_size < needed) {
        fprintf(stderr, "kernel_launch: ws_size %zu < needed %zu\n", ws_size, needed);
        return;
    }

    k_proj_qk<<<BS, 256, 0, stream>>>(x, Wks, Wqs, Q, Kf, Qb, Kb);
    k_cumsum<<<HB, 256, 0, stream>>>(Kf, cumK);
    k_den<<<64, 256, 0, stream>>>(Q, cumK, den);
    k_proj_v<<<dim3(4, 32, PH), 256, 0, stream>>>(x, Wvs, Vt);
    k_att_zero<<<dim3(15, HB), 256, 0, stream>>>(att);
    k_fused<<<dim3(16, HB), 256, 0, stream>>>(Qb, Kb, den, Vt, att, node);
    k_out_part<<<dim3(4, 32, 4), 256, 0, stream>>>(node, Wo, part);
    k_reduce<<<512, 256, 0, stream>>>(part, out);
}

// Round 4
// 120.887 us; speedup vs baseline: 3.6914x; 1.3462x over previous
//
#include <hip/hip_runtime.h>
#include <hip/hip_bf16.h>
#include <cstdio>

// Problem constants: B=2, S=1024, D=256, H=8, K=32
#define PB 2
#define PS 1024
#define PD 256
#define PK 32
#define HB (PH*PB)          // 16
#define PH 8
#define BS (PB*PS)          // 2048
#define EPS 1e-9f

typedef __attribute__((ext_vector_type(8))) short bf16x8;
typedef __attribute__((ext_vector_type(4))) float f32x4;

__device__ inline unsigned short f2bf(float f) {
    __hip_bfloat16 h = __float2bfloat16(f);
    return *reinterpret_cast<unsigned short*>(&h);
}

// ---------------- kernel A: x -> bf16 ---------------------------------------
__global__ void k_xb(const float* __restrict__ x, unsigned short* __restrict__ xb) {
    int i = blockIdx.x*256 + threadIdx.x;       // 131072 float4s
    float4 v = ((const float4*)x)[i];
    ushort4 o = {f2bf(v.x), f2bf(v.y), f2bf(v.z), f2bf(v.w)};
    ((ushort4*)xb)[i] = o;
}

// ---------------- kernel B: Wq/Wk [h][d 256][kk 32] -> [h][kk][d] bf16 ------
__global__ void k_transpose_qk(const float* __restrict__ Wqs, const float* __restrict__ Wks,
                               unsigned short* __restrict__ WqT, unsigned short* __restrict__ WkT) {
    int h = blockIdx.x;
    const float* S = (blockIdx.y ? Wks : Wqs) + (size_t)h*8192;
    unsigned short* D = (blockIdx.y ? WkT : WqT) + (size_t)h*8192;
    __shared__ float T[256*33];
    int tid = threadIdx.x;
#pragma unroll
    for (int p = 0; p < 32; ++p) {
        int idx = p*256 + tid;                  // d*32 + kk
        T[(idx>>5)*33 + (idx&31)] = S[idx];
    }
    __syncthreads();
#pragma unroll
    for (int p = 0; p < 8; ++p) {
        int o4 = p*256 + tid;                   // ushort4 idx: flat = kk*256 + d
        int kk = o4 >> 6, d = (o4 & 63)*4;
        ushort4 o;
        o.x = f2bf(T[(d+0)*33 + kk]); o.y = f2bf(T[(d+1)*33 + kk]);
        o.z = f2bf(T[(d+2)*33 + kk]); o.w = f2bf(T[(d+3)*33 + kk]);
        *(ushort4*)(D + (size_t)kk*256 + d) = o;
    }
}

// ---------------- kernel C: 256x256 per-head transpose f32 -> bf16 ----------
// dst(h, e, d) = src(h, d, e);  dst addr = h*head_stride + e*row_stride + d
__global__ void k_transpose256(const float* __restrict__ src, unsigned short* __restrict__ dst,
                               int dst_row_stride, int dst_head_stride) {
    int e0 = blockIdx.x*64, d0 = blockIdx.y*64, h = blockIdx.z;
    __shared__ float T[64][69];
    const float* S = src + (size_t)h*65536;
    int ty = threadIdx.x>>4, c4 = threadIdx.x&15;
#pragma unroll
    for (int p = 0; p < 4; ++p) {
        int r = p*16 + ty;                      // d row
        float4 v = *(const float4*)(S + (size_t)(d0+r)*256 + e0 + c4*4);
        T[r][c4*4+0]=v.x; T[r][c4*4+1]=v.y; T[r][c4*4+2]=v.z; T[r][c4*4+3]=v.w;
    }
    __syncthreads();
    unsigned short* D = dst + (size_t)h*dst_head_stride;
#pragma unroll
    for (int p = 0; p < 4; ++p) {
        int er = p*16 + ty;                     // e row
        ushort4 o;
        o.x = f2bf(T[c4*4+0][er]); o.y = f2bf(T[c4*4+1][er]);
        o.z = f2bf(T[c4*4+2][er]); o.w = f2bf(T[c4*4+3][er]);
        *(ushort4*)(D + (size_t)(e0+er)*dst_row_stride + d0 + c4*4) = o;
    }
}

// ---------------- kernel 1: Q/K projection via MFMA + elu+1 ------------------
// grid (32 m-tiles, 2 {Q,K}, 4 n-tiles); A = xb [bs][d], B = WqT/WkT [col][d].
__global__ __launch_bounds__(256) void k_proj_qk_mfma(
    const unsigned short* __restrict__ xb, const unsigned short* __restrict__ WqT,
    const unsigned short* __restrict__ WkT,
    float* __restrict__ Q, float* __restrict__ Kf,
    unsigned short* __restrict__ Qb, unsigned short* __restrict__ Kb)
{
    int m0 = blockIdx.x*64;
    int isK = blockIdx.y;
    int n0 = blockIdx.z*64;
    const unsigned short* W = isK ? WkT : WqT;
    int tid = threadIdx.x, w = tid>>6, l15 = tid&15, g = (tid>>4)&3;
    f32x4 zf = {0.f,0.f,0.f,0.f};
    f32x4 acc[4] = {zf,zf,zf,zf};
    const unsigned short* arow = xb + (size_t)(m0+16*w+l15)*256 + 8*g;
#pragma unroll
    for (int kk = 0; kk < 8; ++kk) {
        bf16x8 af = *(const bf16x8*)(arow + kk*32);
#pragma unroll
        for (int nt = 0; nt < 4; ++nt) {
            bf16x8 bf = *(const bf16x8*)(W + (size_t)(n0+16*nt+l15)*256 + kk*32 + 8*g);
            acc[nt] = __builtin_amdgcn_mfma_f32_16x16x32_bf16(af, bf, acc[nt], 0, 0, 0);
        }
    }
    int bs_base = m0 + 16*w + 4*g;
#pragma unroll
    for (int nt = 0; nt < 4; ++nt) {
        int col = n0 + 16*nt + l15;             // h*32 + kk
        int h = col>>5, kk = col&31;
#pragma unroll
        for (int j = 0; j < 4; ++j) {
            int bs = bs_base + j;
            int b = bs>>10, s = bs&1023;
            float z = acc[nt][j];
            z = z > 0.f ? z + 1.f : expf(z);
            size_t idx = ((size_t)(h*PB+b)*PS + s)*PK + kk;
            if (isK) { Kf[idx] = z; Kb[idx] = f2bf(z); }
            else     { Q[idx]  = z; Qb[idx] = f2bf(z); }
        }
    }
}

// ---------------- kernel 2: cumsum of K' over s ------------------------------
__global__ void k_cumsum(const float* __restrict__ Kf, float* __restrict__ cumK) {
    int hb  = blockIdx.x;
    int tid = threadIdx.x;
    int c = tid >> 5, kk = tid & 31;
    const float* src = Kf   + hb*(PS*PK) + c*128*PK + kk;
    float*       dst = cumK + hb*(PS*PK) + c*128*PK + kk;
    float sum = 0.f;
#pragma unroll 8
    for (int i = 0; i < 128; ++i) sum += src[i*PK];
    __shared__ float ssum[8][32];
    ssum[c][kk] = sum;
    __syncthreads();
    float acc = 0.f;
    for (int j = 0; j < c; ++j) acc += ssum[j][kk];
#pragma unroll 8
    for (int i = 0; i < 128; ++i) { acc += src[i*PK]; dst[i*PK] = acc; }
}

// ---------------- kernel 3: den[hb,s] = q . cumK + EPS -----------------------
__global__ void k_den(const float* __restrict__ Q, const float* __restrict__ cumK,
                      float* __restrict__ den) {
    int i = blockIdx.x*256 + threadIdx.x;
    const float4* q  = (const float4*)(Q    + (size_t)i*PK);
    const float4* ck = (const float4*)(cumK + (size_t)i*PK);
    float acc = 0.f;
#pragma unroll
    for (int j = 0; j < 8; ++j) {
        float4 a = q[j], b = ck[j];
        acc += a.x*b.x + a.y*b.y + a.z*b.z + a.w*b.w;
    }
    den[i] = acc + EPS;
}

// ---------------- kernel 4: V projection via MFMA -> Vt bf16 -----------------
// Vt layout: [h*32 + bsTile][e 256][t 64] bf16.
__global__ __launch_bounds__(256) void k_proj_v_mfma(
    const unsigned short* __restrict__ xb, const unsigned short* __restrict__ WvT,
    unsigned short* __restrict__ Vt)
{
    int e0 = blockIdx.x*64, m0 = blockIdx.y*64, h = blockIdx.z;
    int tid = threadIdx.x, w = tid>>6, l15 = tid&15, g = (tid>>4)&3;
    f32x4 zf = {0.f,0.f,0.f,0.f};
    f32x4 acc[4] = {zf,zf,zf,zf};
    const unsigned short* arow = xb + (size_t)(m0+16*w+l15)*256 + 8*g;
    const unsigned short* Wb = WvT + (size_t)h*65536;
#pragma unroll
    for (int kk = 0; kk < 8; ++kk) {
        bf16x8 af = *(const bf16x8*)(arow + kk*32);
#pragma unroll
        for (int nt = 0; nt < 4; ++nt) {
            bf16x8 bf = *(const bf16x8*)(Wb + (size_t)(e0+16*nt+l15)*256 + kk*32 + 8*g);
            acc[nt] = __builtin_amdgcn_mfma_f32_16x16x32_bf16(af, bf, acc[nt], 0, 0, 0);
        }
    }
    unsigned short* VtT = Vt + ((size_t)h*32 + blockIdx.y)*(256*64);
#pragma unroll
    for (int nt = 0; nt < 4; ++nt) {
        ushort4 o = {f2bf(acc[nt][0]), f2bf(acc[nt][1]), f2bf(acc[nt][2]), f2bf(acc[nt][3])};
        *(ushort4*)(VtT + (size_t)(e0+16*nt+l15)*64 + 16*w + 4*g) = o;
    }
}

// ---------------- kernel 5: zero-fill strictly-upper att tiles ---------------
__global__ void k_att_zero(float* __restrict__ att) {
    int st = blockIdx.x;           // 0..14
    int hb = blockIdx.y;
    int s0 = st * 64;
    int c0 = s0 + 64;
    int nz4 = (PS - c0) >> 2;
    float* base = att + (size_t)hb*PS*PS + (size_t)s0*PS + c0;
    int r = threadIdx.x >> 2;
    int l4 = threadIdx.x & 3;
    float4 z = {0.f, 0.f, 0.f, 0.f};
    for (int c4 = l4; c4 < nz4; c4 += 4)
        *(float4*)(base + (size_t)r*PS + c4*4) = z;
}

// ---------------- kernel 6: fused MFMA att + node ----------------------------
__global__ __launch_bounds__(256) void k_fused(
    const unsigned short* __restrict__ Qb, const unsigned short* __restrict__ Kb,
    const float* __restrict__ den, const unsigned short* __restrict__ Vt,
    float* __restrict__ att, unsigned short* __restrict__ nodeB)
{
    int yy = blockIdx.x;
    int st = (yy & 1) ? (15 - (yy >> 1)) : (yy >> 1);
    int hb = blockIdx.y;
    int s0 = st * 64;
    int tid = threadIdx.x;
    int w = tid >> 6, l15 = tid & 15, g = (tid >> 4) & 3;

    __shared__ unsigned short VtL[256*72];   // 36 KB
    __shared__ unsigned short PL[64*72];     // 9 KB
    __shared__ float rden[64];

    bf16x8 qf = *(const bf16x8*)(Qb + ((size_t)hb*PS + s0 + 16*w + l15)*PK + 8*g);
    if (tid < 64) rden[tid] = 1.0f / den[hb*PS + s0 + tid];

    f32x4 zf = {0.f, 0.f, 0.f, 0.f};
    f32x4 acc2[4][4];
#pragma unroll
    for (int i = 0; i < 4; ++i)
#pragma unroll
        for (int j = 0; j < 4; ++j) acc2[i][j] = zf;

    float* attb = att + (size_t)hb*PS*PS;

    for (int t0 = 0; t0 <= s0; t0 += 64) {
        __syncthreads();
        const float4* src = (const float4*)(Vt + ((size_t)hb*16 + (t0 >> 6))*(256*64));
#pragma unroll
        for (int rep = 0; rep < 8; ++rep) {
            int idx = tid + rep*256;
            float4 v = src[idx];
            int e = idx >> 3, q = idx & 7;
            *(float4*)(VtL + e*72 + q*8) = v;
        }
        f32x4 p[4];
#pragma unroll
        for (int nt = 0; nt < 4; ++nt) {
            bf16x8 kf = *(const bf16x8*)(Kb + ((size_t)hb*PS + t0 + 16*nt + l15)*PK + 8*g);
            p[nt] = __builtin_amdgcn_mfma_f32_16x16x32_bf16(qf, kf, zf, 0, 0, 0);
        }
        bool diag = (t0 == s0);
        int rb = 16*w + 4*g;
#pragma unroll
        for (int nt = 0; nt < 4; ++nt) {
#pragma unroll
            for (int j = 0; j < 4; ++j) {
                int r = rb + j;
                int t = t0 + 16*nt + l15;
                float v = p[nt][j] * rden[r];
                if (diag && t > s0 + r) v = 0.f;
                attb[(size_t)(s0 + r)*PS + t] = v;
                PL[r*72 + 16*nt + l15] = f2bf(v);
            }
        }
        __syncthreads();
#pragma unroll
        for (int c = 0; c < 2; ++c) {
            bf16x8 af[4];
#pragma unroll
            for (int mt = 0; mt < 4; ++mt)
                af[mt] = *(const bf16x8*)(PL + (16*mt + l15)*72 + 32*c + 8*g);
#pragma unroll
            for (int ntl = 0; ntl < 4; ++ntl) {
                bf16x8 vf = *(const bf16x8*)(VtL + (16*(4*w + ntl) + l15)*72 + 32*c + 8*g);
#pragma unroll
                for (int mt = 0; mt < 4; ++mt)
                    acc2[mt][ntl] = __builtin_amdgcn_mfma_f32_16x16x32_bf16(af[mt], vf, acc2[mt][ntl], 0, 0, 0);
            }
        }
    }
    // store nodeB bf16 [bs 2048][h*256+d 2048]
    int h = hb >> 1, b = hb & 1;
    unsigned short* np = nodeB + ((size_t)(b*PS + s0))*2048 + h*256;
#pragma unroll
    for (int mt = 0; mt < 4; ++mt)
#pragma unroll
        for (int ntl = 0; ntl < 4; ++ntl)
#pragma unroll
            for (int j = 0; j < 4; ++j)
                np[(size_t)(16*mt + 4*g + j)*2048 + 64*w + 16*ntl + l15] = f2bf(acc2[mt][ntl][j]);
}

// ---------------- kernel 7: out = nodeB @ WoT via MFMA (K-split 2) -----------
__global__ __launch_bounds__(256) void k_out_mfma(
    const unsigned short* __restrict__ nodeB, const unsigned short* __restrict__ WoT,
    float* __restrict__ part)
{
    int e0 = blockIdx.x*64, m0 = blockIdx.y*64, kz = blockIdx.z;
    int tid = threadIdx.x, w = tid>>6, l15 = tid&15, g = (tid>>4)&3;
    f32x4 zf = {0.f,0.f,0.f,0.f};
    f32x4 acc[4] = {zf,zf,zf,zf};
    const unsigned short* arow = nodeB + (size_t)(m0+16*w+l15)*2048 + kz*1024 + 8*g;
    const unsigned short* brow = WoT + kz*1024 + 8*g;
#pragma unroll
    for (int kk = 0; kk < 32; ++kk) {
        bf16x8 af = *(const bf16x8*)(arow + kk*32);
#pragma unroll
        for (int nt = 0; nt < 4; ++nt) {
            bf16x8 bf = *(const bf16x8*)(brow + (size_t)(e0+16*nt+l15)*2048 + kk*32);
            acc[nt] = __builtin_amdgcn_mfma_f32_16x16x32_bf16(af, bf, acc[nt], 0, 0, 0);
        }
    }
    float* P = part + (size_t)kz*BS*PD;
#pragma unroll
    for (int nt = 0; nt < 4; ++nt)
#pragma unroll
        for (int j = 0; j < 4; ++j)
            P[(size_t)(m0+16*w+4*g+j)*PD + e0+16*nt+l15] = acc[nt][j];
}

// ---------------- kernel 8: reduce 2 partials -> out --------------------------
__global__ void k_reduce2(const float* __restrict__ part, float* __restrict__ out) {
    int i = blockIdx.x*256 + threadIdx.x;      // float4 index, 0..131071
    const float4* p = (const float4*)part;
    float4 a = p[i], b = p[131072 + i];
    float4 o = {a.x+b.x, a.y+b.y, a.z+b.z, a.w+b.w};
    ((float4*)out)[i] = o;
}

// ---------------- launch ------------------------------------------------------
extern "C" void kernel_launch(void* const* d_in, const int* in_sizes, int n_in,
                              void* d_out, int out_size, void* d_ws, size_t ws_size,
                              hipStream_t stream) {
    const float* x   = (const float*)d_in[0];
    const float* Wks = (const float*)d_in[1];
    const float* Wqs = (const float*)d_in[2];
    const float* Wvs = (const float*)d_in[3];
    const float* Wo  = (const float*)d_in[4];

    float* out = (float*)d_out;                     // [B,S,D]
    float* att = (float*)d_out + (size_t)PB*PS*PD;  // [H,B,S,S]

    // workspace layout (float offsets)
    float* ws = (float*)d_ws;
    float*          Q     = ws + 0;         //   524,288
    float*          Kf    = ws + 524288;    //   524,288
    float*          cumK  = ws + 1048576;   //   524,288
    float*          den   = ws + 1572864;   //    16,384
    unsigned short* Qb    = (unsigned short*)(ws + 1589248);  //   524,288 u16
    unsigned short* Kb    = (unsigned short*)(ws + 1851392);  //   524,288 u16
    unsigned short* Vt    = (unsigned short*)(ws + 2113536);  // 4,194,304 u16
    unsigned short* xb    = (unsigned short*)(ws + 4210688);  //   524,288 u16
    unsigned short* WqT   = (unsigned short*)(ws + 4472832);  //    65,536 u16
    unsigned short* WkT   = (unsigned short*)(ws + 4505600);  //    65,536 u16
    unsigned short* WvT   = (unsigned short*)(ws + 4538368);  //   524,288 u16
    unsigned short* WoT   = (unsigned short*)(ws + 4800512);  //   524,288 u16
    unsigned short* nodeB = (unsigned short*)(ws + 5062656);  // 4,194,304 u16
    float*          part  = ws + 7159808;   // 1,048,576
    const size_t needed = (size_t)8208384 * 4;
    if (ws_size < needed) {
        fprintf(stderr, "kernel_launch: ws_size %zu < needed %zu\n", ws_size, needed);
        return;
    }

    k_xb<<<512, 256, 0, stream>>>(x, xb);
    k_transpose_qk<<<dim3(PH, 2), 256, 0, stream>>>(Wqs, Wks, WqT, WkT);
    k_transpose256<<<dim3(4, 4, PH), 256, 0, stream>>>(Wvs, WvT, 256, 65536);
    k_transpose256<<<dim3(4, 4, PH), 256, 0, stream>>>(Wo,  WoT, 2048, 256);
    k_proj_qk_mfma<<<dim3(32, 2, 4), 256, 0, stream>>>(xb, WqT, WkT, Q, Kf, Qb, Kb);
    k_cumsum<<<HB, 256, 0, stream>>>(Kf, cumK);
    k_den<<<64, 256, 0, stream>>>(Q, cumK, den);
    k_proj_v_mfma<<<dim3(4, 32, PH), 256, 0, stream>>>(xb, WvT, Vt);
    k_att_zero<<<dim3(15, HB), 256, 0, stream>>>(att);
    k_fused<<<dim3(16, HB), 256, 0, stream>>>(Qb, Kb, den, Vt, att, nodeB);
    k_out_mfma<<<dim3(4, 32, 2), 256, 0, stream>>>(nodeB, WoT, part);
    k_reduce2<<<512, 256, 0, stream>>>(part, out);
}